// Round 8
// baseline (18001.984 us; speedup 1.0000x reference)
//
#include <hip/hip_runtime.h>
#include <math.h>

namespace {

typedef __attribute__((ext_vector_type(8))) _Float16 h8v;  // 8 x fp16 (one MFMA frag)
typedef __attribute__((ext_vector_type(4))) float f4;
typedef unsigned long long u64;

constexpr int B_ = 128;
constexpr int T_ = 500;
constexpr int F_ = 64;
constexpr int U_ = 512;
constexpr int NCLS_ = 11;
constexpr int HU = B_ * U_;           // 65536
constexpr float R_ON_ = 0.05f;
constexpr float ALPHA_ = 0.001f;
constexpr float LO_SCALE = 1.0f / 2048.0f;

constexpr int GRID_BLOCKS = 64;       // 32 cell0(+cls) + 32 cell1
constexpr int NGRP = 8;
constexpr int GSZ = 8;                // 8*8 = 64
constexpr int NPH = 502;

union hu16 { ushort u; _Float16 h; };
__device__ __forceinline__ ushort f2h_bits(float f) { hu16 v; v.h = (_Float16)f; return v.u; }
__device__ __forceinline__ float h_bits2f(ushort b) { hu16 v; v.u = b; return (float)v.h; }

__device__ __forceinline__ void st_u64(ushort* p, u64 v) {
  __hip_atomic_store((u64*)p, v, __ATOMIC_RELAXED, __HIP_MEMORY_SCOPE_AGENT);
}
__device__ __forceinline__ u64 ld_u64(const ushort* p) {
  return __hip_atomic_load((const u64*)p, __ATOMIC_RELAXED, __HIP_MEMORY_SCOPE_AGENT);
}
__device__ __forceinline__ u64 pack4(const ushort* h) {
  return (u64)h[0] | ((u64)h[1] << 16) | ((u64)h[2] << 32) | ((u64)h[3] << 48);
}

// LLC-coherent (L1/L2-bypass) 16B load. ASYNC: valid only after wait0().
#define LDH8(dst, src) \
  asm volatile("global_load_dwordx4 %0, %1, off sc0 sc1" : "=&v"(dst) : "v"(src))

__device__ __forceinline__ void wait0() {
  asm volatile("s_waitcnt vmcnt(0)" ::: "memory");
  __builtin_amdgcn_sched_barrier(0);
}

// fragment element offset (in ushorts) for state element (b, k), k in [0,512)
__device__ __forceinline__ int foff(int b, int k) {
  return (((k >> 5) * 8 + (b >> 4)) * 64 + ((b & 15) | (((k >> 3) & 3) << 4))) * 8 + (k & 7);
}

// Fence-free hierarchical grid barrier over monotonic counters at LLC.
__device__ __forceinline__ void phase_barrier(unsigned* grp, unsigned* root,
                                              unsigned* gen, int gid, unsigned ph) {
  asm volatile("s_waitcnt vmcnt(0)" ::: "memory");   // drain write-through stores
  __syncthreads();
  if (threadIdx.x == 0) {
    const unsigned old =
        __hip_atomic_fetch_add(&grp[gid * 32], 1u, __ATOMIC_RELAXED, __HIP_MEMORY_SCOPE_AGENT);
    if (old == ph * GSZ + (GSZ - 1)) {
      const unsigned r =
          __hip_atomic_fetch_add(root, 1u, __ATOMIC_RELAXED, __HIP_MEMORY_SCOPE_AGENT);
      if (r == ph * NGRP + (NGRP - 1)) {
        __hip_atomic_store(gen, ph + 1u, __ATOMIC_RELAXED, __HIP_MEMORY_SCOPE_AGENT);
      }
    }
    unsigned it = 0;
    for (;;) {
      const unsigned cur = ((++it & 255u) == 0u)
          ? __hip_atomic_load(gen, __ATOMIC_ACQUIRE, __HIP_MEMORY_SCOPE_AGENT)
          : __hip_atomic_load(gen, __ATOMIC_RELAXED, __HIP_MEMORY_SCOPE_AGENT);
      if (cur >= ph + 1u) break;
      __builtin_amdgcn_s_sleep(2);
    }
  }
  __syncthreads();
}

// Persistent weight fragments: fp16 hi + (lo * 2^11), full precision via 2 accs.
template <int NKS>
__device__ void load_weights_f16(
    h8v (&wh)[NKS], h8v (&wl)[NKS],
    const float* __restrict__ W1, int K1, const float* __restrict__ W2,
    int n, int kbase, int krow)
{
#pragma unroll
  for (int ks = 0; ks < NKS; ++ks) {
#pragma unroll
    for (int j = 0; j < 8; ++j) {
      const int kg = kbase + ks * 32 + krow + j;
      const float wv = (kg < K1) ? W1[(size_t)kg * 2048 + n]
                                 : W2[(size_t)(kg - K1) * 2048 + n];
      const _Float16 hi = (_Float16)wv;
      wh[ks][j] = hi;
      wl[ks][j] = (_Float16)((wv - (float)hi) * 2048.0f);
    }
  }
}

// Fused PhasedLSTM elementwise for 4 units; c/h_old in registers (f32, exact).
__device__ __forceinline__ void elem_update4(
    const float* __restrict__ z_s, int b, int t, int u0, int uoff,
    const float* __restrict__ bias, const float* __restrict__ tau,
    const float* __restrict__ shift, const float* __restrict__ timesT,
    float (&cc)[4], float (&hh)[4], ushort* __restrict__ hw)
{
  const float tt = timesT[t * B_ + b];
  ushort vh[4];
#pragma unroll
  for (int uu = 0; uu < 4; ++uu) {
    const int ub = uoff + uu;
    const int u = u0 + ub;
    const float zi = z_s[(4 * ub + 0) * 133 + b] + bias[u];
    const float zf = z_s[(4 * ub + 1) * 133 + b] + bias[512 + u];
    const float zg = z_s[(4 * ub + 2) * 133 + b] + bias[1024 + u];
    const float zo = z_s[(4 * ub + 3) * 133 + b] + bias[1536 + u];

    const float ig = 1.f / (1.f + expf(-zi));
    const float fg = 1.f / (1.f + expf(-zf));
    const float gg = tanhf(zg);
    const float og = 1.f / (1.f + expf(-zo));

    const float c_old = cc[uu];
    const float c_t = fg * c_old + ig * gg;
    const float h_t = og * tanhf(c_t);

    const float tau_u = tau[u];
    float phi = fmodf(tt - shift[u], tau_u);
    if (phi < 0.f) phi += tau_u;
    phi /= tau_u;
    float kt;
    if (phi < 0.5f * R_ON_)      kt = phi * (2.0f / R_ON_);
    else if (phi < R_ON_)        kt = 2.0f - phi * (2.0f / R_ON_);
    else                         kt = ALPHA_ * phi;

    const float cn = kt * c_t + (1.0f - kt) * c_old;
    const float hn = kt * h_t + (1.0f - kt) * hh[uu];
    cc[uu] = cn;
    hh[uu] = hn;
    vh[uu] = f2h_bits(hn);
  }
  st_u64(hw + foff(b, u0 + uoff), pack4(vh));
}

// Full classifier row (512-dot + softmax) by one wave, fp16 state input.
__device__ __forceinline__ void classifier_row(
    int b, int t, const ushort* __restrict__ h1p,
    const float* __restrict__ wfc, const float* __restrict__ bfc,
    float* __restrict__ out, int lane)
{
  const int u = lane * 8;
  const int e = foff(b, u);
  const u64 d0 = ld_u64(h1p + e);
  const u64 d1 = ld_u64(h1p + e + 4);
  float acc[NCLS_];
#pragma unroll
  for (int c = 0; c < NCLS_; ++c) acc[c] = 0.f;
#pragma unroll
  for (int j = 0; j < 8; ++j) {
    const ushort hb = (ushort)(((j < 4) ? d0 : d1) >> (16 * (j & 3)));
    const float h = h_bits2f(hb);
    const float* wr = wfc + (size_t)(u + j) * NCLS_;
#pragma unroll
    for (int c = 0; c < NCLS_; ++c) acc[c] = fmaf(h, wr[c], acc[c]);
  }
#pragma unroll
  for (int off = 32; off >= 1; off >>= 1) {
#pragma unroll
    for (int c = 0; c < NCLS_; ++c) acc[c] += __shfl_xor(acc[c], off, 64);
  }
  if (lane == 0) {
    float lg[NCLS_];
    float m = -1e30f;
#pragma unroll
    for (int c = 0; c < NCLS_; ++c) { lg[c] = acc[c] + bfc[c]; m = fmaxf(m, lg[c]); }
    float s = 0.f;
#pragma unroll
    for (int c = 0; c < NCLS_; ++c) { lg[c] = expf(lg[c] - m); s += lg[c]; }
    const float inv = 1.0f / s;
    float* op = out + ((size_t)b * T_ + t) * NCLS_;
#pragma unroll
    for (int c = 0; c < NCLS_; ++c) op[c] = lg[c] * inv;
  }
}

__global__ void init_kernel(unsigned* state_u32, const float* times, float* timesT,
                            unsigned* bar) {
  const int i = blockIdx.x * blockDim.x + threadIdx.x;
  if (i < 2 * HU) state_u32[i] = 0u;          // 4*HU ushorts of fp16 state
  if (i < T_ * B_) {
    const int t = i >> 7, b = i & 127;
    timesT[i] = times[b * T_ + t];
  }
  if (i < 4096) bar[i] = 0u;
}

// Phase ph: cell0 t=ph (blocks 0..31, 16 units, + classifier t=ph-2, 4 rows),
// cell1 t=ph-1 (blocks 32..63, 16 units). 512 thr = 8 waves = 4 ct x 2 kh.
// A-state is staged per row-tile into LDS (read ONCE per block from LLC),
// double-buffered across the 8 row-tiles.
__global__ __launch_bounds__(512, 2) void plstm_kernel(
    const float* __restrict__ inputs,
    const float* __restrict__ k0, const float* __restrict__ rk0,
    const float* __restrict__ b0, const float* __restrict__ tau0, const float* __restrict__ s0,
    const float* __restrict__ k1, const float* __restrict__ rk1,
    const float* __restrict__ b1, const float* __restrict__ tau1, const float* __restrict__ s1,
    const float* __restrict__ wfc, const float* __restrict__ bfc,
    float* __restrict__ out,
    ushort* __restrict__ h0s, ushort* __restrict__ h1s,
    const float* __restrict__ timesT,
    unsigned* __restrict__ bar)
{
  __shared__ __align__(16) float z_s[64 * 133];          // 34 KB
  __shared__ __align__(16) ushort abuf[2][32 * 64 * 8];  // 2 x 32 KB

  const int bid = blockIdx.x;
  const int tid = threadIdx.x;
  const int w = tid >> 6;
  const int lane = tid & 63;
  const int ct = w & 3;
  const int kh = w >> 2;
  const int krow = (lane >> 4) * 8;
  const int c_loc = ct * 16 + (lane & 15);
  const int rbase = (lane >> 4) * 4;
  const int gid = bid >> 3;
  const int b_el = tid & 127;
  const int uoff = (tid >> 7) * 4;
  unsigned* grp = bar;
  unsigned* root = bar + NGRP * 32;
  unsigned* gen = root + 32;

  if (bid < 32) {
    // ---- cell 0: K = 576 = x(64) + h0(512). Stage h0 (16 chunks/rt).
    //      kh0: 9 wt chunks (2 x + staged 0..6); kh1: 9 wt chunks (staged 7..15)
    const int u0 = bid * 16;
    const int n = (c_loc & 3) * 512 + u0 + (c_loc >> 2);
    h8v wh[9], wl[9];
    load_weights_f16<9>(wh, wl, k0, 64, rk0, n, kh * 288, krow);
    float cc[4], hh[4];
#pragma unroll
    for (int i = 0; i < 4; ++i) { cc[i] = 0.f; hh[i] = 0.f; }

    for (unsigned ph = 0; ph < NPH; ++ph) {
      const bool work = ph < T_;
      if (work) {
        for (int i = tid; i < 64 * 133; i += 512) z_s[i] = 0.f;

        const ushort* Ah0 = h0s + (size_t)(ph & 1) * HU;
        h8v sreg[2];
        // prologue: stage rt=0
#pragma unroll
        for (int i = 0; i < 2; ++i) {
          const int s = tid + i * 512, kb = s >> 6, ln = s & 63;
          LDH8(sreg[i], Ah0 + ((size_t)(kb * 8 + 0) * 64 + ln) * 8);
        }
        wait0();
#pragma unroll
        for (int i = 0; i < 2; ++i) {
          const int s = tid + i * 512;
          *(h8v*)(&abuf[0][0] + (size_t)s * 8) = sreg[i];
        }
        __syncthreads();

#pragma unroll 1
        for (int rt = 0; rt < 8; ++rt) {
          if (rt < 7) {
#pragma unroll
            for (int i = 0; i < 2; ++i) {
              const int s = tid + i * 512, kb = s >> 6, ln = s & 63;
              LDH8(sreg[i], Ah0 + ((size_t)(kb * 8 + rt + 1) * 64 + ln) * 8);
            }
          }
          const ushort* bp = &abuf[rt & 1][0];
          f4 a0 = {0.f, 0.f, 0.f, 0.f};
          f4 a1 = {0.f, 0.f, 0.f, 0.f};
          f4 x0a, x0b, x1a, x1b;
          if (kh == 0) {
            const float* xp = inputs +
                ((size_t)(rt * 16 + (lane & 15)) * T_ + ph) * F_ + krow;
            x0a = *(const f4*)xp;        x0b = *(const f4*)(xp + 4);
            x1a = *(const f4*)(xp + 32); x1b = *(const f4*)(xp + 36);
          }
#pragma unroll
          for (int ks = 0; ks < 9; ++ks) {
            h8v frag;
            if (kh == 0 && ks < 2) {
              const f4 va = ks ? x1a : x0a;
              const f4 vb = ks ? x1b : x0b;
#pragma unroll
              for (int j = 0; j < 4; ++j) {
                frag[j] = (_Float16)va[j];
                frag[4 + j] = (_Float16)vb[j];
              }
            } else {
              const int kb = (kh == 0) ? (ks - 2) : (7 + ks);
              frag = *(const h8v*)(bp + ((size_t)(kb * 64 + lane)) * 8);
            }
            a0 = __builtin_amdgcn_mfma_f32_16x16x32_f16(frag, wh[ks], a0, 0, 0, 0);
            a1 = __builtin_amdgcn_mfma_f32_16x16x32_f16(frag, wl[ks], a1, 0, 0, 0);
          }
          const f4 red = a0 + a1 * LO_SCALE;
#pragma unroll
          for (int j = 0; j < 4; ++j)
            atomicAdd(&z_s[c_loc * 133 + rt * 16 + rbase + j], red[j]);
          if (rt < 7) {
            wait0();
#pragma unroll
            for (int i = 0; i < 2; ++i) {
              const int s = tid + i * 512;
              *(h8v*)(&abuf[(rt + 1) & 1][0] + (size_t)s * 8) = sreg[i];
            }
          }
          __syncthreads();
        }

        elem_update4(z_s, b_el, (int)ph, u0, uoff, b0, tau0, s0, timesT,
                     cc, hh, h0s + (size_t)((ph + 1) & 1) * HU);
      }
      if (w < 4 && ph >= 2) {
        classifier_row(bid * 4 + w, (int)ph - 2,
                       h1s + (size_t)((ph + 1) & 1) * HU, wfc, bfc, out, lane);
      }
      if (ph < NPH - 1) phase_barrier(grp, root, gen, gid, ph);
    }
  } else {
    // ---- cell 1: K = 1024 = h0(t)(512) + h1(t-1)(512). Stage 32 chunks/rt.
    const int u0 = (bid - 32) * 16;
    const int n = (c_loc & 3) * 512 + u0 + (c_loc >> 2);
    h8v wh[16], wl[16];
    load_weights_f16<16>(wh, wl, k1, 512, rk1, n, kh * 512, krow);
    float cc[4], hh[4];
#pragma unroll
    for (int i = 0; i < 4; ++i) { cc[i] = 0.f; hh[i] = 0.f; }

    for (unsigned ph = 0; ph < NPH; ++ph) {
      const int t = (int)ph - 1;
      const bool work = (t >= 0 && t < T_);
      if (work) {
        for (int i = tid; i < 64 * 133; i += 512) z_s[i] = 0.f;

        const ushort* Ah0 = h0s + (size_t)(ph & 1) * HU;        // h0(t)
        const ushort* Ah1 = h1s + (size_t)((ph + 1) & 1) * HU;  // h1(t-1)
        h8v sreg[4];
#pragma unroll
        for (int i = 0; i < 4; ++i) {
          const int s = tid + i * 512, kb = s >> 6, ln = s & 63;
          const ushort* src = (kb < 16)
              ? Ah0 + ((size_t)(kb * 8 + 0) * 64 + ln) * 8
              : Ah1 + ((size_t)((kb - 16) * 8 + 0) * 64 + ln) * 8;
          LDH8(sreg[i], src);
        }
        wait0();
#pragma unroll
        for (int i = 0; i < 4; ++i) {
          const int s = tid + i * 512;
          *(h8v*)(&abuf[0][0] + (size_t)s * 8) = sreg[i];
        }
        __syncthreads();

#pragma unroll 1
        for (int rt = 0; rt < 8; ++rt) {
          if (rt < 7) {
#pragma unroll
            for (int i = 0; i < 4; ++i) {
              const int s = tid + i * 512, kb = s >> 6, ln = s & 63;
              const ushort* src = (kb < 16)
                  ? Ah0 + ((size_t)(kb * 8 + rt + 1) * 64 + ln) * 8
                  : Ah1 + ((size_t)((kb - 16) * 8 + rt + 1) * 64 + ln) * 8;
              LDH8(sreg[i], src);
            }
          }
          const ushort* bp = &abuf[rt & 1][0];
          f4 a0 = {0.f, 0.f, 0.f, 0.f};
          f4 a1 = {0.f, 0.f, 0.f, 0.f};
#pragma unroll
          for (int g = 0; g < 2; ++g) {
            h8v st[8];
#pragma unroll
            for (int k8 = 0; k8 < 8; ++k8)
              st[k8] = *(const h8v*)(bp + ((size_t)((kh * 16 + g * 8 + k8) * 64 + lane)) * 8);
#pragma unroll
            for (int k8 = 0; k8 < 8; ++k8) {
              a0 = __builtin_amdgcn_mfma_f32_16x16x32_f16(st[k8], wh[g * 8 + k8], a0, 0, 0, 0);
              a1 = __builtin_amdgcn_mfma_f32_16x16x32_f16(st[k8], wl[g * 8 + k8], a1, 0, 0, 0);
            }
          }
          const f4 red = a0 + a1 * LO_SCALE;
#pragma unroll
          for (int j = 0; j < 4; ++j)
            atomicAdd(&z_s[c_loc * 133 + rt * 16 + rbase + j], red[j]);
          if (rt < 7) {
            wait0();
#pragma unroll
            for (int i = 0; i < 4; ++i) {
              const int s = tid + i * 512;
              *(h8v*)(&abuf[(rt + 1) & 1][0] + (size_t)s * 8) = sreg[i];
            }
          }
          __syncthreads();
        }

        elem_update4(z_s, b_el, t, u0, uoff, b1, tau1, s1, timesT,
                     cc, hh, h1s + (size_t)(ph & 1) * HU);
      }
      if (ph < NPH - 1) phase_barrier(grp, root, gen, gid, ph);
    }
  }
}

}  // namespace

extern "C" void kernel_launch(void* const* d_in, const int* in_sizes, int n_in,
                              void* d_out, int out_size, void* d_ws, size_t ws_size,
                              hipStream_t stream) {
  const float* inputs = (const float*)d_in[0];
  const float* times  = (const float*)d_in[1];
  const float* k0     = (const float*)d_in[2];
  const float* rk0    = (const float*)d_in[3];
  const float* b0     = (const float*)d_in[4];
  const float* tau0   = (const float*)d_in[5];
  const float* s0     = (const float*)d_in[6];
  const float* k1     = (const float*)d_in[7];
  const float* rk1    = (const float*)d_in[8];
  const float* b1     = (const float*)d_in[9];
  const float* tau1   = (const float*)d_in[10];
  const float* s1     = (const float*)d_in[11];
  const float* wfc    = (const float*)d_in[12];
  const float* bfc    = (const float*)d_in[13];
  float* out = (float*)d_out;

  ushort* h0s = (ushort*)d_ws;             // [2][HU] fp16
  ushort* h1s = h0s + 2 * HU;              // [2][HU] fp16
  float* timesT = (float*)(h1s + 2 * HU);  // [T][B]
  unsigned* bar = (unsigned*)(timesT + T_ * B_);

  hipLaunchKernelGGL(init_kernel, dim3(512), dim3(256), 0, stream,
                     (unsigned*)d_ws, times, timesT, bar);
  hipLaunchKernelGGL(plstm_kernel, dim3(GRID_BLOCKS), dim3(512), 0, stream,
                     inputs, k0, rk0, b0, tau0, s0,
                     k1, rk1, b1, tau1, s1, wfc, bfc, out,
                     h0s, h1s, timesT, bar);
}

// Round 9
// 13365.221 us; speedup vs baseline: 1.3469x; 1.3469x over previous
//
#include <hip/hip_runtime.h>
#include <math.h>

namespace {

typedef __attribute__((ext_vector_type(8))) _Float16 h8v;  // 8 x fp16 (one MFMA frag)
typedef __attribute__((ext_vector_type(4))) float f4;
typedef unsigned long long u64;

constexpr int B_ = 128;
constexpr int T_ = 500;
constexpr int F_ = 64;
constexpr int U_ = 512;
constexpr int NCLS_ = 11;
constexpr int HU = B_ * U_;           // 65536
constexpr float R_ON_ = 0.05f;
constexpr float ALPHA_ = 0.001f;
constexpr float LO_SCALE = 1.0f / 2048.0f;

constexpr int NBLK = 128;             // 64 cell0(+cls) + 64 cell1
constexpr int NPH = 502;

union hu16 { ushort u; _Float16 h; };
__device__ __forceinline__ ushort f2h_bits(float f) { hu16 v; v.h = (_Float16)f; return v.u; }
__device__ __forceinline__ float h_bits2f(ushort b) { hu16 v; v.u = b; return (float)v.h; }

__device__ __forceinline__ void st_u64(ushort* p, u64 v) {
  __hip_atomic_store((u64*)p, v, __ATOMIC_RELAXED, __HIP_MEMORY_SCOPE_AGENT);
}
__device__ __forceinline__ u64 ld_u64(const ushort* p) {
  return __hip_atomic_load((const u64*)p, __ATOMIC_RELAXED, __HIP_MEMORY_SCOPE_AGENT);
}
__device__ __forceinline__ u64 pack4(const ushort* h) {
  return (u64)h[0] | ((u64)h[1] << 16) | ((u64)h[2] << 32) | ((u64)h[3] << 48);
}

// LLC-coherent (L1/L2-bypass) 16B load. ASYNC: valid only after a covering wait.
#define LDH8(dst, src) \
  asm volatile("global_load_dwordx4 %0, %1, off sc0 sc1" : "=&v"(dst) : "v"(src))

__device__ __forceinline__ void wait0()  { asm volatile("s_waitcnt vmcnt(0)"  ::: "memory"); __builtin_amdgcn_sched_barrier(0); }
__device__ __forceinline__ void wait8()  { asm volatile("s_waitcnt vmcnt(8)"  ::: "memory"); __builtin_amdgcn_sched_barrier(0); }
__device__ __forceinline__ void wait16() { asm volatile("s_waitcnt vmcnt(16)" ::: "memory"); __builtin_amdgcn_sched_barrier(0); }

// fragment element offset (in ushorts) for state element (b, k), k in [0,512)
__device__ __forceinline__ int foff(int b, int k) {
  return (((k >> 5) * 8 + (b >> 4)) * 64 + ((b & 15) | (((k >> 3) & 3) << 4))) * 8 + (k & 7);
}

// RMW-free grid barrier: per-block flag STORES (own 64B slot each; parallel
// LLC commits), block 0 aggregates with 128 parallel spinner lanes, then
// publishes gen. Monotonic values (ph+1), no reset, relaxed everywhere.
// Visibility: state is write-through (agent atomics) drained by vmcnt(0);
// state loads bypass L1/L2 (sc0 sc1).
__device__ __forceinline__ void flag_barrier(unsigned* flags, unsigned* gen,
                                             int bid, int tid, unsigned ph) {
  asm volatile("s_waitcnt vmcnt(0)" ::: "memory");
  __syncthreads();
  if (tid == 0)
    __hip_atomic_store(&flags[bid * 16], ph + 1u, __ATOMIC_RELAXED, __HIP_MEMORY_SCOPE_AGENT);
  if (bid == 0) {
    if (tid < NBLK) {
      while (__hip_atomic_load(&flags[tid * 16], __ATOMIC_RELAXED,
                               __HIP_MEMORY_SCOPE_AGENT) < ph + 1u)
        __builtin_amdgcn_s_sleep(2);
    }
    __syncthreads();
    if (tid == 0)
      __hip_atomic_store(gen, ph + 1u, __ATOMIC_RELAXED, __HIP_MEMORY_SCOPE_AGENT);
  } else {
    if (tid == 0) {
      while (__hip_atomic_load(gen, __ATOMIC_RELAXED,
                               __HIP_MEMORY_SCOPE_AGENT) < ph + 1u)
        __builtin_amdgcn_s_sleep(4);
    }
    __syncthreads();
  }
}

// Persistent weight fragments: fp16 hi + (lo * 2^11), full precision via 2 accs.
template <int NKS>
__device__ void load_weights_f16(
    h8v* wh, h8v* wl,
    const float* __restrict__ W1, int K1, const float* __restrict__ W2,
    int n, int kbase, int krow)
{
#pragma unroll
  for (int ks = 0; ks < NKS; ++ks) {
#pragma unroll
    for (int j = 0; j < 8; ++j) {
      const int kg = kbase + ks * 32 + krow + j;
      const float wv = (kg < K1) ? W1[(size_t)kg * 2048 + n]
                                 : W2[(size_t)(kg - K1) * 2048 + n];
      const _Float16 hi = (_Float16)wv;
      wh[ks][j] = hi;
      wl[ks][j] = (_Float16)((wv - (float)hi) * 2048.0f);
    }
  }
}

// Fused PhasedLSTM elementwise for 4 units; c/h_old in f32 registers.
__device__ __forceinline__ void elem_update4(
    const float* __restrict__ z_s, int b, int t, int u0, int uoff,
    const float* __restrict__ bias, const float* __restrict__ tau,
    const float* __restrict__ shift, const float* __restrict__ timesT,
    float (&cc)[4], float (&hh)[4], ushort* __restrict__ hw)
{
  const float tt = timesT[t * B_ + b];
  ushort vh[4];
#pragma unroll
  for (int uu = 0; uu < 4; ++uu) {
    const int ub = uoff + uu;
    const int u = u0 + ub;
    const float zi = z_s[(4 * ub + 0) * 133 + b] + bias[u];
    const float zf = z_s[(4 * ub + 1) * 133 + b] + bias[512 + u];
    const float zg = z_s[(4 * ub + 2) * 133 + b] + bias[1024 + u];
    const float zo = z_s[(4 * ub + 3) * 133 + b] + bias[1536 + u];

    const float ig = 1.f / (1.f + expf(-zi));
    const float fg = 1.f / (1.f + expf(-zf));
    const float gg = tanhf(zg);
    const float og = 1.f / (1.f + expf(-zo));

    const float c_old = cc[uu];
    const float c_t = fg * c_old + ig * gg;
    const float h_t = og * tanhf(c_t);

    const float tau_u = tau[u];
    float phi = fmodf(tt - shift[u], tau_u);
    if (phi < 0.f) phi += tau_u;
    phi /= tau_u;
    float kt;
    if (phi < 0.5f * R_ON_)      kt = phi * (2.0f / R_ON_);
    else if (phi < R_ON_)        kt = 2.0f - phi * (2.0f / R_ON_);
    else                         kt = ALPHA_ * phi;

    const float cn = kt * c_t + (1.0f - kt) * c_old;
    const float hn = kt * h_t + (1.0f - kt) * hh[uu];
    cc[uu] = cn;
    hh[uu] = hn;
    vh[uu] = f2h_bits(hn);
  }
  st_u64(hw + foff(b, u0 + uoff), pack4(vh));
}

__global__ void init_kernel(unsigned* state_u32, const float* times, float* timesT,
                            unsigned* bar) {
  const int i = blockIdx.x * blockDim.x + threadIdx.x;
  if (i < 2 * HU) state_u32[i] = 0u;          // 4*HU ushorts of fp16 state
  if (i < T_ * B_) {
    const int t = i >> 7, b = i & 127;
    timesT[i] = times[b * T_ + t];
  }
  if (i < 4096) bar[i] = 0u;
}

// Phase ph: cell0 t=ph (blocks 0..63, 8 units, + cls t=ph-2, 2 rows each),
// cell1 t=ph-1 (blocks 64..127, 8 units). One flag-barrier per phase.
__global__ __launch_bounds__(256, 1) void plstm_kernel(
    const float* __restrict__ inputs,
    const float* __restrict__ k0, const float* __restrict__ rk0,
    const float* __restrict__ b0, const float* __restrict__ tau0, const float* __restrict__ s0,
    const float* __restrict__ k1, const float* __restrict__ rk1,
    const float* __restrict__ b1, const float* __restrict__ tau1, const float* __restrict__ s1,
    const float* __restrict__ wfc, const float* __restrict__ bfc,
    float* __restrict__ out,
    ushort* __restrict__ h0s, ushort* __restrict__ h1s,
    const float* __restrict__ timesT,
    unsigned* __restrict__ bar)
{
  __shared__ __align__(16) float z_s[32 * 133];   // 17 KB
  __shared__ float cls_s[4][12];

  const int bid = blockIdx.x;
  const int tid = threadIdx.x;
  const int w = tid >> 6;
  const int lane = tid & 63;
  const int krow = (lane >> 4) * 8;
  const int rbase = (lane >> 4) * 4;
  const int b_el = tid & 127;
  const int uoff = (tid >> 7) * 4;
  unsigned* flags = bar;
  unsigned* gen = bar + NBLK * 16;

  int nct[2];
#pragma unroll
  for (int ct = 0; ct < 2; ++ct) {
    const int c = ct * 16 + (lane & 15);
    nct[ct] = (c & 3) * 512 + ((bid & 63) * 8) + (c >> 2);
  }

  if (bid < 64) {
    // ---- cell 0: K = 576 (x 64 + h0 512); waves: ksl(2) x rh(2), 2 ct each.
    //      ksl0: wt chunks {x0,x1, h0 kb0..7} (10); ksl1: {h0 kb8..15} (8).
    const int u0 = bid * 8;
    const int ksl = w & 1;
    const int rh = w >> 1;
    h8v wh[2][10], wl[2][10];
#pragma unroll
    for (int ct = 0; ct < 2; ++ct) {
      if (ksl == 0) load_weights_f16<10>(&wh[ct][0], &wl[ct][0], k0, 64, rk0, nct[ct], 0, krow);
      else          load_weights_f16<8>(&wh[ct][0], &wl[ct][0], k0, 64, rk0, nct[ct], 320, krow);
    }
    float cc[4], hh[4];
#pragma unroll
    for (int i = 0; i < 4; ++i) { cc[i] = 0.f; hh[i] = 0.f; }

    for (unsigned ph = 0; ph < NPH; ++ph) {
      const bool work = ph < T_;
      if (work) {
        for (int i = tid; i < 32 * 133; i += 256) z_s[i] = 0.f;
      }
      __syncthreads();
      if (work) {
        const ushort* A = h0s + (size_t)(ph & 1) * HU;
        const int kb0 = ksl * 8;
        const int wof = (ksl == 0) ? 2 : 0;
        // x preload + convert (ksl0 only): rows rh*64 + rt*16 + (lane&15)
        h8v xf[4][2];
        if (ksl == 0) {
#pragma unroll
          for (int rt = 0; rt < 4; ++rt) {
            const float* xp = inputs +
                ((size_t)(rh * 64 + rt * 16 + (lane & 15)) * T_ + ph) * F_ + krow;
            const f4 va = *(const f4*)xp;
            const f4 vb = *(const f4*)(xp + 4);
            const f4 vc = *(const f4*)(xp + 32);
            const f4 vd = *(const f4*)(xp + 36);
#pragma unroll
            for (int j = 0; j < 4; ++j) {
              xf[rt][0][j] = (_Float16)va[j];
              xf[rt][0][4 + j] = (_Float16)vb[j];
              xf[rt][1][j] = (_Float16)vc[j];
              xf[rt][1][4 + j] = (_Float16)vd[j];
            }
          }
        }
        __builtin_amdgcn_sched_barrier(0);

        h8v stA[8], stB[8];
#define C0_ISSUE(ST, R) do { \
  _Pragma("unroll") \
  for (int k8_ = 0; k8_ < 8; ++k8_) \
    LDH8(ST[k8_], A + ((size_t)((kb0 + k8_) * 8 + rh * 4 + (R)) * 64 + lane) * 8); \
} while (0)
#define C0_MM(ST, R) do { \
  _Pragma("unroll") \
  for (int ct_ = 0; ct_ < 2; ++ct_) { \
    f4 a0 = {0.f, 0.f, 0.f, 0.f}; \
    f4 a1 = {0.f, 0.f, 0.f, 0.f}; \
    if (ksl == 0) { \
      _Pragma("unroll") \
      for (int xk_ = 0; xk_ < 2; ++xk_) { \
        a0 = __builtin_amdgcn_mfma_f32_16x16x32_f16(xf[R][xk_], wh[ct_][xk_], a0, 0, 0, 0); \
        a1 = __builtin_amdgcn_mfma_f32_16x16x32_f16(xf[R][xk_], wl[ct_][xk_], a1, 0, 0, 0); \
      } \
    } \
    _Pragma("unroll") \
    for (int k8_ = 0; k8_ < 8; ++k8_) { \
      a0 = __builtin_amdgcn_mfma_f32_16x16x32_f16(ST[k8_], wh[ct_][wof + k8_], a0, 0, 0, 0); \
      a1 = __builtin_amdgcn_mfma_f32_16x16x32_f16(ST[k8_], wl[ct_][wof + k8_], a1, 0, 0, 0); \
    } \
    const f4 red = a0 + a1 * LO_SCALE; \
    const int cl_ = ct_ * 16 + (lane & 15); \
    _Pragma("unroll") \
    for (int j_ = 0; j_ < 4; ++j_) \
      atomicAdd(&z_s[cl_ * 133 + (rh * 4 + (R)) * 16 + rbase + j_], red[j_]); \
  } \
} while (0)
        C0_ISSUE(stA, 0);
        C0_ISSUE(stB, 1);
        wait8();  C0_MM(stA, 0); C0_ISSUE(stA, 2);
        wait8();  C0_MM(stB, 1); C0_ISSUE(stB, 3);
        wait8();  C0_MM(stA, 2);
        wait0();  C0_MM(stB, 3);
#undef C0_ISSUE
#undef C0_MM
      }
      __syncthreads();
      if (work) {
        elem_update4(z_s, b_el, (int)ph, u0, uoff, b0, tau0, s0, timesT,
                     cc, hh, h0s + (size_t)((ph + 1) & 1) * HU);
      }
      // classifier for t = ph-2 (reads h1 parity (ph+1)&1, written phase ph-1)
      if (ph >= 2) {
        const int bcls = 2 * bid + (w >> 1);
        const int idx = ((w & 1) << 6) | lane;   // 0..127
        const int u = idx * 4;
        const ushort* h1p = h1s + (size_t)((ph + 1) & 1) * HU;
        const u64 du = ld_u64(h1p + foff(bcls, u));
        float acc[NCLS_];
#pragma unroll
        for (int c = 0; c < NCLS_; ++c) acc[c] = 0.f;
#pragma unroll
        for (int j = 0; j < 4; ++j) {
          const float h = h_bits2f((ushort)(du >> (16 * j)));
          const float* wr = wfc + (size_t)(u + j) * NCLS_;
#pragma unroll
          for (int c = 0; c < NCLS_; ++c) acc[c] = fmaf(h, wr[c], acc[c]);
        }
#pragma unroll
        for (int off = 32; off >= 1; off >>= 1) {
#pragma unroll
          for (int c = 0; c < NCLS_; ++c) acc[c] += __shfl_xor(acc[c], off, 64);
        }
        if (lane == 0) {
#pragma unroll
          for (int c = 0; c < NCLS_; ++c) cls_s[w][c] = acc[c];
        }
      }
      __syncthreads();
      if (ph >= 2 && tid < 2) {
        const int t_cl = (int)ph - 2;
        const int bcls = 2 * bid + tid;
        float lg[NCLS_];
        float m = -1e30f;
#pragma unroll
        for (int c = 0; c < NCLS_; ++c) {
          lg[c] = cls_s[2 * tid][c] + cls_s[2 * tid + 1][c] + bfc[c];
          m = fmaxf(m, lg[c]);
        }
        float s = 0.f;
#pragma unroll
        for (int c = 0; c < NCLS_; ++c) { lg[c] = expf(lg[c] - m); s += lg[c]; }
        const float inv = 1.0f / s;
        float* op = out + ((size_t)bcls * T_ + t_cl) * NCLS_;
#pragma unroll
        for (int c = 0; c < NCLS_; ++c) op[c] = lg[c] * inv;
      }
      if (ph < NPH - 1) flag_barrier(flags, gen, bid, tid, ph);
    }
  } else {
    // ---- cell 1: K = 1024 (h0(t) 512 + h1(t-1) 512); waves: ksl(4), 2 ct,
    //      8 rt each, 3-deep counted-vmcnt pipeline.
    const int u0 = (bid - 64) * 8;
    const int ksl = w;
    h8v wh[2][8], wl[2][8];
#pragma unroll
    for (int ct = 0; ct < 2; ++ct)
      load_weights_f16<8>(&wh[ct][0], &wl[ct][0], k1, 512, rk1, nct[ct], ksl * 256, krow);
    float cc[4], hh[4];
#pragma unroll
    for (int i = 0; i < 4; ++i) { cc[i] = 0.f; hh[i] = 0.f; }

    for (unsigned ph = 0; ph < NPH; ++ph) {
      const int t = (int)ph - 1;
      const bool work = (t >= 0 && t < T_);
      if (work) {
        for (int i = tid; i < 32 * 133; i += 256) z_s[i] = 0.f;
      }
      __syncthreads();
      if (work) {
        const ushort* A = (ksl < 2) ? h0s + (size_t)(ph & 1) * HU
                                    : h1s + (size_t)((ph + 1) & 1) * HU;
        const int kbb = (ksl & 1) * 8;
        h8v s0[8], s1[8], s2[8];
#define C1_ISSUE(ST, R) do { \
  _Pragma("unroll") \
  for (int k8_ = 0; k8_ < 8; ++k8_) \
    LDH8(ST[k8_], A + ((size_t)((kbb + k8_) * 8 + (R)) * 64 + lane) * 8); \
} while (0)
#define C1_MM(ST, R) do { \
  _Pragma("unroll") \
  for (int ct_ = 0; ct_ < 2; ++ct_) { \
    f4 a0 = {0.f, 0.f, 0.f, 0.f}; \
    f4 a1 = {0.f, 0.f, 0.f, 0.f}; \
    _Pragma("unroll") \
    for (int k8_ = 0; k8_ < 8; ++k8_) { \
      a0 = __builtin_amdgcn_mfma_f32_16x16x32_f16(ST[k8_], wh[ct_][k8_], a0, 0, 0, 0); \
      a1 = __builtin_amdgcn_mfma_f32_16x16x32_f16(ST[k8_], wl[ct_][k8_], a1, 0, 0, 0); \
    } \
    const f4 red = a0 + a1 * LO_SCALE; \
    const int cl_ = ct_ * 16 + (lane & 15); \
    _Pragma("unroll") \
    for (int j_ = 0; j_ < 4; ++j_) \
      atomicAdd(&z_s[cl_ * 133 + (R) * 16 + rbase + j_], red[j_]); \
  } \
} while (0)
        C1_ISSUE(s0, 0);
        C1_ISSUE(s1, 1);
        C1_ISSUE(s2, 2);
        wait16(); C1_MM(s0, 0); C1_ISSUE(s0, 3);
        wait16(); C1_MM(s1, 1); C1_ISSUE(s1, 4);
        wait16(); C1_MM(s2, 2); C1_ISSUE(s2, 5);
        wait16(); C1_MM(s0, 3); C1_ISSUE(s0, 6);
        wait16(); C1_MM(s1, 4); C1_ISSUE(s1, 7);
        wait16(); C1_MM(s2, 5);
        wait8();  C1_MM(s0, 6);
        wait0();  C1_MM(s1, 7);
#undef C1_ISSUE
#undef C1_MM
      }
      __syncthreads();
      if (work) {
        elem_update4(z_s, b_el, t, u0, uoff, b1, tau1, s1, timesT,
                     cc, hh, h1s + (size_t)(ph & 1) * HU);
      }
      if (ph < NPH - 1) flag_barrier(flags, gen, bid, tid, ph);
    }
  }
}

}  // namespace

extern "C" void kernel_launch(void* const* d_in, const int* in_sizes, int n_in,
                              void* d_out, int out_size, void* d_ws, size_t ws_size,
                              hipStream_t stream) {
  const float* inputs = (const float*)d_in[0];
  const float* times  = (const float*)d_in[1];
  const float* k0     = (const float*)d_in[2];
  const float* rk0    = (const float*)d_in[3];
  const float* b0     = (const float*)d_in[4];
  const float* tau0   = (const float*)d_in[5];
  const float* s0     = (const float*)d_in[6];
  const float* k1     = (const float*)d_in[7];
  const float* rk1    = (const float*)d_in[8];
  const float* b1     = (const float*)d_in[9];
  const float* tau1   = (const float*)d_in[10];
  const float* s1     = (const float*)d_in[11];
  const float* wfc    = (const float*)d_in[12];
  const float* bfc    = (const float*)d_in[13];
  float* out = (float*)d_out;

  ushort* h0s = (ushort*)d_ws;             // [2][HU] fp16
  ushort* h1s = h0s + 2 * HU;              // [2][HU] fp16
  float* timesT = (float*)(h1s + 2 * HU);  // [T][B]
  unsigned* bar = (unsigned*)(timesT + T_ * B_);

  hipLaunchKernelGGL(init_kernel, dim3(512), dim3(256), 0, stream,
                     (unsigned*)d_ws, times, timesT, bar);
  hipLaunchKernelGGL(plstm_kernel, dim3(NBLK), dim3(256), 0, stream,
                     inputs, k0, rk0, b0, tau0, s0,
                     k1, rk1, b1, tau1, s1, wfc, bfc, out,
                     h0s, h1s, timesT, bar);
}